// Round 8
// baseline (146.377 us; speedup 1.0000x reference)
//
#include <hip/hip_runtime.h>
#include <math.h>

#define M_GRID 128
#define J_FEAT 80
#define NNET   160   // NBASE*J_FEAT
#define HDIM   256

typedef __attribute__((ext_vector_type(8))) short v8s;   // 8 bf16
typedef __attribute__((ext_vector_type(4))) float f4;    // MFMA accum / float4

__device__ __forceinline__ unsigned short f2bf(float f) {
    unsigned u = __float_as_uint(f);
    u += 0x7fffu + ((u >> 16) & 1u);   // round-to-nearest-even
    return (unsigned short)(u >> 16);
}

__device__ __forceinline__ float selu_f(float x) {
    const float SC = 1.0507009873554805f;
    const float AL = 1.6732632423543772f;
    return x > 0.f ? SC * x : SC * AL * (__expf(x) - 1.f);
}

// One workgroup per network n. 512 threads = 8 waves (2 waves/SIMD -> real TLP),
// wave w owns rows 16w..16w+15; acc[16] f4 = 64 AGPRs (pinned "+a"), afrag 32
// VGPRs. Per-wave unified budget is 2048/8 = 256 -> arch target <=192 (fits).
//
// W streaming (per layer, 8 K-stages of 32 k-rows):
//   thread (j=tid&255, o8=tid>>8) loads its j-column's 16 fp32 (k = 32s+16*o8+i,
//   stride 1 KB; per-instruction across 256 threads each k-row is a contiguous
//   1 KB -> fully coalesced), converts to 2x v8s, ds_writes into the
//   XOR-swizzled bf16 tile [256 j][32 k] (double-buffered, 16 KB each).
//   Loads are issued TWO stages ahead (3 rotating reg sets, statically
//   unrolled) so ~2 stages of HBM/L3 latency hide under MFMA+staging.
//   Sync = ONE raw s_barrier per stage (+ lgkmcnt(0) + sched_barrier fence);
//   NO hand-written vmcnt -- every wait is compiler-counted on exact regs.
// Input layer: wi/bi/la/lb staged to LDS once; two passes over LDS with an
//   asm memory clobber between them so the compiler cannot CSE 128 values
//   into live registers (the round-6/7 spill source).
// Inter-layer C->A transpose via per-wave 8 KB scr (wave-private, lgkm only).
// Next layer's first two stages are prefetched before each epilogue (T14).
// LDS 100 KB: tiles 2x16K @0, scr 8x8K @32768, params 4K @98304.
__attribute__((amdgpu_flat_work_group_size(512, 512), amdgpu_waves_per_eu(1, 1)))
__global__ void basis_kernel(const float* __restrict__ t,
                             const float* __restrict__ W_in,
                             const float* __restrict__ b_in,
                             const float* __restrict__ W_h,
                             const float* __restrict__ b_h,
                             const float* __restrict__ W_out,
                             const float* __restrict__ b_out,
                             const float* __restrict__ ln_a,
                             const float* __restrict__ ln_b,
                             float* __restrict__ basesT)   // [M][NNET]
{
    extern __shared__ __align__(16) unsigned char lds[];   // 100 KiB
    const int n    = blockIdx.x;
    const int tid  = threadIdx.x;
    const int l    = tid & 63;
    const int wv   = tid >> 6;      // wave 0..7
    const int lr   = l & 15;
    const int g    = l >> 4;        // k-group
    const int jcol = tid & 255;     // staging column
    const int o8   = tid >> 8;      // staging k-half (0/1)

    float* const p_wi = (float*)(lds + 98304);
    float* const p_bi = p_wi + 256;
    float* const p_la = p_bi + 256;
    float* const p_lb = p_la + 256;
    unsigned char* const scr = lds + 32768 + (size_t)wv * 8192;

    // ---------------- stage input params to LDS ----------------
    if (tid < 256) {
        p_wi[tid] = W_in[(size_t)n * HDIM + tid];
        p_bi[tid] = b_in[(size_t)n * HDIM + tid];
    } else {
        const int t2 = tid - 256;
        p_la[t2] = ln_a[(size_t)n * HDIM + t2];
        p_lb[t2] = ln_b[(size_t)n * HDIM + t2];
    }
    __syncthreads();

    // ---------------- input layer (2 passes over LDS, no reg bloat) -------
    const float tval = t[wv * 16 + lr];
    v8s afrag[8];
    {
        float s = 0.f, q = 0.f;
        #pragma unroll
        for (int kt = 0; kt < 8; ++kt) {
            const int h0 = kt * 32 + g * 8;
            const f4 w0 = *(const f4*)(p_wi + h0), w1 = *(const f4*)(p_wi + h0 + 4);
            const f4 b0 = *(const f4*)(p_bi + h0), b1 = *(const f4*)(p_bi + h0 + 4);
            #pragma unroll
            for (int i = 0; i < 4; ++i) {
                float v0 = __builtin_fmaf(tval, w0[i], b0[i]);
                float v1 = __builtin_fmaf(tval, w1[i], b1[i]);
                s += v0 + v1; q += v0 * v0 + v1 * v1;
            }
        }
        s += __shfl_xor(s, 16); q += __shfl_xor(q, 16);
        s += __shfl_xor(s, 32); q += __shfl_xor(q, 32);
        const float mean = s * (1.f / 256.f);
        const float var  = (q - s * s * (1.f / 256.f)) * (1.f / 255.f); // unbiased
        const float inv  = 1.f / (sqrtf(var) + 1e-6f);                  // eps on std
        asm volatile("" ::: "memory");   // forbid CSE of pass-1 LDS reads
        #pragma unroll
        for (int kt = 0; kt < 8; ++kt) {
            const int h0 = kt * 32 + g * 8;
            const f4 w0 = *(const f4*)(p_wi + h0), w1 = *(const f4*)(p_wi + h0 + 4);
            const f4 b0 = *(const f4*)(p_bi + h0), b1 = *(const f4*)(p_bi + h0 + 4);
            const f4 a0 = *(const f4*)(p_la + h0), a1 = *(const f4*)(p_la + h0 + 4);
            const f4 e0 = *(const f4*)(p_lb + h0), e1 = *(const f4*)(p_lb + h0 + 4);
            v8s a;
            #pragma unroll
            for (int i = 0; i < 4; ++i) {
                float v0 = __builtin_fmaf(tval, w0[i], b0[i]);
                float v1 = __builtin_fmaf(tval, w1[i], b1[i]);
                a[i]     = (short)f2bf(selu_f(v0 + (v0 - mean) * inv * a0[i] + e0[i]));
                a[i + 4] = (short)f2bf(selu_f(v1 + (v1 - mean) * inv * a1[i] + e1[i]));
            }
            afrag[kt] = a;
        }
    }

    // ---------------- staging helpers ----------------
    float rr[3][16];
    auto load_set = [&](int set, const float* Wl, int s) {
        const float* base = Wl + (size_t)(s * 32 + o8 * 16) * HDIM + jcol;
        #pragma unroll
        for (int i = 0; i < 16; ++i) rr[set][i] = base[(size_t)i * HDIM];
    };
    auto write_tile = [&](int set, int s) {
        const int tb = (s & 1) << 14;
        #pragma unroll
        for (int oct = 0; oct < 2; ++oct) {
            v8s pk;
            #pragma unroll
            for (int i = 0; i < 8; ++i) pk[i] = (short)f2bf(rr[set][oct * 8 + i]);
            int byte = tb + jcol * 64 + o8 * 32 + oct * 16;
            byte ^= (jcol & 3) << 4;
            *(v8s*)(lds + byte) = pk;
        }
    };

    f4 acc[16];
    const float* Wl = W_h + (size_t)n * (HDIM * HDIM);
    load_set(0, Wl, 0);
    load_set(1, Wl, 1);

    #pragma unroll 1
    for (int L = 0; L < 3; ++L) {
        const f4 zero = {0.f, 0.f, 0.f, 0.f};
        #pragma unroll
        for (int ct = 0; ct < 16; ++ct) {
            acc[ct] = zero;
            asm volatile("" : "+a"(acc[ct]));   // pin to AGPR side
        }

        #pragma unroll
        for (int s = 0; s < 8; ++s) {
            if (s < 6) load_set((s + 2) % 3, Wl, s + 2);
            write_tile(s % 3, s);
            asm volatile("s_waitcnt lgkmcnt(0)" ::: "memory");
            __builtin_amdgcn_sched_barrier(0);
            __builtin_amdgcn_s_barrier();       // tile (s&1) fully written
            #pragma unroll
            for (int ct = 0; ct < 16; ++ct) {
                const int jb = ct * 16 + lr;
                int byte = ((s & 1) << 14) + jb * 64 + g * 16;
                byte ^= (jb & 3) << 4;
                const v8s bf = *(const v8s*)(lds + byte);
                acc[ct] = __builtin_amdgcn_mfma_f32_16x16x32_bf16(
                    afrag[s], bf, acc[ct], 0, 0, 0);
            }
        }

        // prefetch next layer's first two stages under the epilogue (T14)
        const float* Wn = W_h + ((size_t)(L + 1) * NNET + n) * (HDIM * HDIM);
        if (L < 2) { load_set(0, Wn, 0); load_set(1, Wn, 1); Wl = Wn; }

        // ---------------- epilogue ----------------
        const float* bh = b_h  + ((size_t)L * NNET + n) * HDIM;
        const float* la = ln_a + ((size_t)(L + 1) * NNET + n) * HDIM;
        const float* lb = ln_b + ((size_t)(L + 1) * NNET + n) * HDIM;

        float sums[4] = {0,0,0,0}, sqs[4] = {0,0,0,0};
        #pragma unroll
        for (int ct = 0; ct < 16; ++ct) {
            const float bias = bh[ct * 16 + lr];
            #pragma unroll
            for (int r = 0; r < 4; ++r) {
                float v = acc[ct][r] + bias;
                acc[ct][r] = v;
                sums[r] += v; sqs[r] += v * v;
            }
        }
        #pragma unroll
        for (int r = 0; r < 4; ++r)
            #pragma unroll
            for (int m = 1; m <= 8; m <<= 1) {
                sums[r] += __shfl_xor(sums[r], m);
                sqs[r]  += __shfl_xor(sqs[r],  m);
            }
        float mean[4], inv[4];
        #pragma unroll
        for (int r = 0; r < 4; ++r) {
            mean[r] = sums[r] * (1.f / 256.f);
            float var = (sqs[r] - sums[r] * sums[r] * (1.f / 256.f)) * (1.f / 255.f);
            inv[r] = 1.f / (sqrtf(var) + 1e-6f);
        }

        if (L < 2) {
            // C layout (row=4g+r, col=ct*16+lr) -> wave-private scr -> afrag
            #pragma unroll
            for (int ct = 0; ct < 16; ++ct) {
                const float a_ = la[ct * 16 + lr], b_ = lb[ct * 16 + lr];
                #pragma unroll
                for (int r = 0; r < 4; ++r) {
                    float v  = acc[ct][r];
                    float sv = selu_f(v + (v - mean[r]) * inv[r] * a_ + b_);
                    const int row  = 4 * g + r;
                    const int byte = (row * 512 + (ct * 16 + lr) * 2) ^ (row << 5);
                    *(unsigned short*)(scr + byte) = f2bf(sv);
                }
            }
            asm volatile("s_waitcnt lgkmcnt(0)" ::: "memory");  // own writes done
            __builtin_amdgcn_sched_barrier(0);
            #pragma unroll
            for (int kt = 0; kt < 8; ++kt) {
                const int byte = (lr * 512 + (kt * 32 + g * 8) * 2) ^ (lr << 5);
                afrag[kt] = *(const v8s*)(scr + byte);
            }
        } else {
            // fused output layer
            const float* wo = W_out + (size_t)n * HDIM;
            const float bo  = b_out[n];
            float ps[4] = {0,0,0,0};
            #pragma unroll
            for (int ct = 0; ct < 16; ++ct) {
                const float a_ = la[ct * 16 + lr], b_ = lb[ct * 16 + lr];
                const float w_ = wo[ct * 16 + lr];
                #pragma unroll
                for (int r = 0; r < 4; ++r) {
                    float v  = acc[ct][r];
                    float sv = selu_f(v + (v - mean[r]) * inv[r] * a_ + b_);
                    ps[r] += sv * w_;
                }
            }
            #pragma unroll
            for (int r = 0; r < 4; ++r)
                #pragma unroll
                for (int m = 1; m <= 8; m <<= 1)
                    ps[r] += __shfl_xor(ps[r], m);
            #pragma unroll
            for (int r = 0; r < 4; ++r)
                if (lr == r)
                    basesT[(size_t)(wv * 16 + 4 * g + r) * NNET + n] = ps[r] + bo;
        }
    }
}

// score[b, jk] = sum_m x[b,m,jk>>1] * basesT[m][jk] * w[m]
__launch_bounds__(256)
__global__ void score_kernel(const float* __restrict__ x,
                             const float* __restrict__ t,
                             const float* __restrict__ basesT,
                             float* __restrict__ out)
{
    __shared__ float c_lds[M_GRID * 32];
    const int jt  = blockIdx.x;   // 0..4
    const int bt  = blockIdx.y;   // 0..255
    const int tid = threadIdx.x;

    for (int i = tid; i < M_GRID * 32; i += 256) {
        const int m  = i >> 5;
        const int jl = i & 31;
        const float tp = t[m == M_GRID - 1 ? M_GRID - 1 : m + 1];
        const float tm = t[m == 0 ? 0 : m - 1];
        c_lds[i] = basesT[(size_t)m * NNET + jt * 32 + jl] * 0.5f * (tp - tm);
    }
    __syncthreads();

    const int jj = tid & 31;
    const int bs = tid >> 5;
    const int jk = jt * 32 + jj;
    const int b  = bt * 8 + bs;
    const float* xp = x + (size_t)b * (M_GRID * J_FEAT) + (jk >> 1);
    float acc = 0.f;
    #pragma unroll 8
    for (int m = 0; m < M_GRID; ++m)
        acc += xp[(size_t)m * J_FEAT] * c_lds[m * 32 + jj];
    out[(size_t)b * NNET + jk] = acc;
}

extern "C" void kernel_launch(void* const* d_in, const int* in_sizes, int n_in,
                              void* d_out, int out_size, void* d_ws, size_t ws_size,
                              hipStream_t stream)
{
    const float* x     = (const float*)d_in[0];
    const float* t     = (const float*)d_in[1];
    const float* W_in  = (const float*)d_in[2];
    const float* b_in  = (const float*)d_in[3];
    const float* W_h   = (const float*)d_in[4];
    const float* b_h   = (const float*)d_in[5];
    const float* W_out = (const float*)d_in[6];
    const float* b_out = (const float*)d_in[7];
    const float* ln_a  = (const float*)d_in[8];
    const float* ln_b  = (const float*)d_in[9];
    float* basesT = (float*)d_ws;   // 128*160*4 = 80 KiB

    basis_kernel<<<dim3(NNET), dim3(512), 102400, stream>>>(
        t, W_in, b_in, W_h, b_h, W_out, b_out, ln_a, ln_b, basesT);
    score_kernel<<<dim3(5, 256), dim3(256), 0, stream>>>(
        x, t, basesT, (float*)d_out);
}

// Round 9
// 127.323 us; speedup vs baseline: 1.1497x; 1.1497x over previous
//
#include <hip/hip_runtime.h>
#include <math.h>

#define M_GRID 128
#define J_FEAT 80
#define NNET   160   // NBASE*J_FEAT
#define HDIM   256

typedef __attribute__((ext_vector_type(8))) short v8s;   // 8 bf16
typedef __attribute__((ext_vector_type(4))) float f4;    // MFMA accum / float4

__device__ __forceinline__ unsigned short f2bf(float f) {
    unsigned u = __float_as_uint(f);
    u += 0x7fffu + ((u >> 16) & 1u);   // round-to-nearest-even
    return (unsigned short)(u >> 16);
}

__device__ __forceinline__ float selu_f(float x) {
    const float SC = 1.0507009873554805f;
    const float AL = 1.6732632423543772f;
    return x > 0.f ? SC * x : SC * AL * (__expf(x) - 1.f);
}

#define FENCE_BAR() do { asm volatile("s_waitcnt lgkmcnt(0)" ::: "memory"); \
                         __builtin_amdgcn_sched_barrier(0);                 \
                         __builtin_amdgcn_s_barrier(); } while (0)

// One workgroup per network n. 512 threads = 8 waves; wave w owns rows
// 16w..16w+15; acc[16] f4 = 64 AGPRs ("+a" pinned); afrag 32 VGPRs.
//
// Staging (rounds 5-8 lesson): global_load_lds gives only ~4-6 GB/s/CU on
// cold HBM (shallow per-CU DMA queue x 900cyc latency) -> use the ordinary
// VMEM path: thread (jcol=tid&255, o8=tid>>8) gathers its j-column's 16 fp32
// (k-rows, each load coalesced 256B/wave across lanes), converts in regs,
// ds_writes the round-7-proven XOR-swizzled bf16 tile [2 khalf][256 j][16 k]
// (double-buffered 2x16KB). TWO 16-reg sets, issued 2 stages ahead; waits
// are compiler-counted on exact registers (no manual vmcnt, nothing to
// corrupt). ONE raw lgkm+s_barrier per stage. Budget: rr 32 + afrag 32 +
// ~40 temps <= 128 arch VGPR at 2 waves/SIMD -> no spill (spill = death,
// rounds 1-8). All input/epilogue params pre-staged to LDS (14 KB).
// LDS 110 KiB dynamic: tiles 2x16K @0, scr 8x8K @32768, params @98304.
__attribute__((amdgpu_flat_work_group_size(512, 512)))
__global__ void basis_kernel(const float* __restrict__ t,
                             const float* __restrict__ W_in,
                             const float* __restrict__ b_in,
                             const float* __restrict__ W_h,
                             const float* __restrict__ b_h,
                             const float* __restrict__ W_out,
                             const float* __restrict__ b_out,
                             const float* __restrict__ ln_a,
                             const float* __restrict__ ln_b,
                             float* __restrict__ basesT)   // [M][NNET]
{
    extern __shared__ __align__(16) unsigned char lds[];   // 112640 B
    const int n    = blockIdx.x;
    const int tid  = threadIdx.x;
    const int l    = tid & 63;
    const int wv   = tid >> 6;      // wave 0..7
    const int lr   = l & 15;
    const int g    = l >> 4;        // k-group
    const int jcol = tid & 255;     // staging column
    const int o8   = tid >> 8;      // staging k-half (0/1)

    float* const P    = (float*)(lds + 98304);
    float* const p_wi = P;               // 256
    float* const p_bi = P + 256;         // 256
    float* const p_wo = P + 512;         // 256
    float* const p_la = P + 768;         // [4][256]
    float* const p_lb = P + 1792;        // [4][256]
    float* const p_bh = P + 2816;        // [3][256]
    unsigned char* const scr = lds + 32768 + (size_t)wv * 8192;

    // -------- staging helpers (round-7-proven tile layout + swizzle) --------
    float rr[2][16];
    auto issue = [&](float (&r)[16], int q) {   // q = global stage 0..23
        const float* Wq = W_h + ((size_t)((q >> 3) * NNET + n) << 16)
                        + (size_t)((q & 7) * 32 + o8 * 16) * HDIM + jcol;
        #pragma unroll
        for (int i = 0; i < 16; ++i) r[i] = Wq[(size_t)i * HDIM];
    };
    auto convert_store = [&](float (&r)[16], int bufp) {
        const int tb = bufp << 14;
        #pragma unroll
        for (int o = 0; o < 2; ++o) {
            v8s pk;
            #pragma unroll
            for (int i = 0; i < 8; ++i) pk[i] = (short)f2bf(r[o * 8 + i]);
            int byte = tb + (o8 << 13) + jcol * 32 + (o << 4);
            byte ^= ((jcol >> 2) & 7) << 4;
            *(v8s*)(lds + byte) = pk;
        }
    };

    issue(rr[0], 0);        // in flight during param staging + input layer
    issue(rr[1], 1);

    // -------- stage all params to LDS --------
    {
        const size_t nb = (size_t)n * HDIM;
        if (tid < 256) {
            p_wi[tid] = W_in[nb + tid];
            p_bi[tid] = b_in[nb + tid];
            p_wo[tid] = W_out[nb + tid];
        } else {
            const int t2 = tid - 256;
            #pragma unroll
            for (int Li = 0; Li < 3; ++Li)
                p_bh[Li * 256 + t2] = b_h[((size_t)Li * NNET + n) * HDIM + t2];
        }
        #pragma unroll
        for (int Li = 0; Li < 4; ++Li) {
            if (tid < 256) p_la[Li * 256 + tid] = ln_a[((size_t)Li * NNET + n) * HDIM + tid];
            else           p_lb[Li * 256 + (tid - 256)] = ln_b[((size_t)Li * NNET + n) * HDIM + (tid - 256)];
        }
    }
    FENCE_BAR();   // params visible (raw barrier: does NOT drain rr loads)

    // -------- input layer (2 passes over LDS params; no reg bloat) --------
    const float tval = t[wv * 16 + lr];
    v8s afrag[8];
    {
        float s = 0.f, q = 0.f;
        #pragma unroll
        for (int kt = 0; kt < 8; ++kt) {
            const int h0 = kt * 32 + g * 8;
            const f4 w0 = *(const f4*)(p_wi + h0), w1 = *(const f4*)(p_wi + h0 + 4);
            const f4 b0 = *(const f4*)(p_bi + h0), b1 = *(const f4*)(p_bi + h0 + 4);
            #pragma unroll
            for (int i = 0; i < 4; ++i) {
                float v0 = __builtin_fmaf(tval, w0[i], b0[i]);
                float v1 = __builtin_fmaf(tval, w1[i], b1[i]);
                s += v0 + v1; q += v0 * v0 + v1 * v1;
            }
        }
        s += __shfl_xor(s, 16); q += __shfl_xor(q, 16);
        s += __shfl_xor(s, 32); q += __shfl_xor(q, 32);
        const float mean = s * (1.f / 256.f);
        const float var  = (q - s * s * (1.f / 256.f)) * (1.f / 255.f); // unbiased
        const float inv  = 1.f / (sqrtf(var) + 1e-6f);                  // eps on std
        asm volatile("" ::: "memory");   // forbid CSE of pass-1 LDS reads
        #pragma unroll
        for (int kt = 0; kt < 8; ++kt) {
            const int h0 = kt * 32 + g * 8;
            const f4 w0 = *(const f4*)(p_wi + h0), w1 = *(const f4*)(p_wi + h0 + 4);
            const f4 b0 = *(const f4*)(p_bi + h0), b1 = *(const f4*)(p_bi + h0 + 4);
            const f4 a0 = *(const f4*)(p_la + h0), a1 = *(const f4*)(p_la + h0 + 4);
            const f4 e0 = *(const f4*)(p_lb + h0), e1 = *(const f4*)(p_lb + h0 + 4);
            v8s a;
            #pragma unroll
            for (int i = 0; i < 4; ++i) {
                float v0 = __builtin_fmaf(tval, w0[i], b0[i]);
                float v1 = __builtin_fmaf(tval, w1[i], b1[i]);
                a[i]     = (short)f2bf(selu_f(v0 + (v0 - mean) * inv * a0[i] + e0[i]));
                a[i + 4] = (short)f2bf(selu_f(v1 + (v1 - mean) * inv * a1[i] + e1[i]));
            }
            afrag[kt] = a;
        }
    }

    convert_store(rr[0], 0);   // compiler inserts the exact vmcnt wait for rr[0]
    FENCE_BAR();               // buf0 ready for all waves

    f4 acc[16];

    #pragma unroll 1
    for (int L = 0; L < 3; ++L) {
        const f4 zero = {0.f, 0.f, 0.f, 0.f};
        #pragma unroll
        for (int ct = 0; ct < 16; ++ct) {
            acc[ct] = zero;
            asm volatile("" : "+a"(acc[ct]));   // pin to AGPR side
        }

        #pragma unroll
        for (int s = 0; s < 8; ++s) {
            // issue stage gs+2 into the set freed by last iteration's convert
            if (L < 2 || s < 6) issue(rr[s & 1], L * 8 + s + 2);
            // MFMA stage s from buf (s&1)
            #pragma unroll
            for (int ct = 0; ct < 16; ++ct) {
                const int jb = ct * 16 + lr;
                int byte = ((s & 1) << 14) + ((g >> 1) << 13) + jb * 32 + ((g & 1) << 4);
                byte ^= ((jb >> 2) & 7) << 4;
                const v8s bf = *(const v8s*)(lds + byte);
                acc[ct] = __builtin_amdgcn_mfma_f32_16x16x32_bf16(
                    afrag[s], bf, acc[ct], 0, 0, 0);
            }
            // convert stage gs+1 (loaded 2 iterations ago) into buf ((s+1)&1)
            if (L < 2 || s < 7) convert_store(rr[(s + 1) & 1], (s + 1) & 1);
            FENCE_BAR();
        }

        // ---------------- epilogue (params from LDS) ----------------
        const float* bh = p_bh + L * 256;
        const float* la = p_la + (L + 1) * 256;
        const float* lb = p_lb + (L + 1) * 256;

        float sums[4] = {0,0,0,0}, sqs[4] = {0,0,0,0};
        #pragma unroll
        for (int ct = 0; ct < 16; ++ct) {
            const float bias = bh[ct * 16 + lr];
            #pragma unroll
            for (int r = 0; r < 4; ++r) {
                float v = acc[ct][r] + bias;
                acc[ct][r] = v;
                sums[r] += v; sqs[r] += v * v;
            }
        }
        #pragma unroll
        for (int r = 0; r < 4; ++r)
            #pragma unroll
            for (int m = 1; m <= 8; m <<= 1) {
                sums[r] += __shfl_xor(sums[r], m);
                sqs[r]  += __shfl_xor(sqs[r],  m);
            }
        float mean[4], inv[4];
        #pragma unroll
        for (int r = 0; r < 4; ++r) {
            mean[r] = sums[r] * (1.f / 256.f);
            float var = (sqs[r] - sums[r] * sums[r] * (1.f / 256.f)) * (1.f / 255.f);
            inv[r] = 1.f / (sqrtf(var) + 1e-6f);
        }

        if (L < 2) {
            // C layout (row=4g+r, col=ct*16+lr) -> wave-private scr -> afrag
            #pragma unroll
            for (int ct = 0; ct < 16; ++ct) {
                const float a_ = la[ct * 16 + lr], b_ = lb[ct * 16 + lr];
                #pragma unroll
                for (int r = 0; r < 4; ++r) {
                    float v  = acc[ct][r];
                    float sv = selu_f(v + (v - mean[r]) * inv[r] * a_ + b_);
                    const int row  = 4 * g + r;
                    const int byte = (row * 512 + (ct * 16 + lr) * 2) ^ (row << 5);
                    *(unsigned short*)(scr + byte) = f2bf(sv);
                }
            }
            asm volatile("s_waitcnt lgkmcnt(0)" ::: "memory");  // own writes done
            __builtin_amdgcn_sched_barrier(0);
            #pragma unroll
            for (int kt = 0; kt < 8; ++kt) {
                const int byte = (lr * 512 + (kt * 32 + g * 8) * 2) ^ (lr << 5);
                afrag[kt] = *(const v8s*)(scr + byte);
            }
        } else {
            // fused output layer
            const float bo = b_out[n];
            float ps[4] = {0,0,0,0};
            #pragma unroll
            for (int ct = 0; ct < 16; ++ct) {
                const float a_ = la[ct * 16 + lr], b_ = lb[ct * 16 + lr];
                const float w_ = p_wo[ct * 16 + lr];
                #pragma unroll
                for (int r = 0; r < 4; ++r) {
                    float v  = acc[ct][r];
                    float sv = selu_f(v + (v - mean[r]) * inv[r] * a_ + b_);
                    ps[r] += sv * w_;
                }
            }
            #pragma unroll
            for (int r = 0; r < 4; ++r)
                #pragma unroll
                for (int m = 1; m <= 8; m <<= 1)
                    ps[r] += __shfl_xor(ps[r], m);
            #pragma unroll
            for (int r = 0; r < 4; ++r)
                if (lr == r)
                    basesT[(size_t)(wv * 16 + 4 * g + r) * NNET + n] = ps[r] + bo;
        }
    }
}

// score[b, jk] = sum_m x[b,m,jk>>1] * basesT[m][jk] * w[m]
__launch_bounds__(256)
__global__ void score_kernel(const float* __restrict__ x,
                             const float* __restrict__ t,
                             const float* __restrict__ basesT,
                             float* __restrict__ out)
{
    __shared__ float c_lds[M_GRID * 32];
    const int jt  = blockIdx.x;   // 0..4
    const int bt  = blockIdx.y;   // 0..255
    const int tid = threadIdx.x;

    for (int i = tid; i < M_GRID * 32; i += 256) {
        const int m  = i >> 5;
        const int jl = i & 31;
        const float tp = t[m == M_GRID - 1 ? M_GRID - 1 : m + 1];
        const float tm = t[m == 0 ? 0 : m - 1];
        c_lds[i] = basesT[(size_t)m * NNET + jt * 32 + jl] * 0.5f * (tp - tm);
    }
    __syncthreads();

    const int jj = tid & 31;
    const int bs = tid >> 5;
    const int jk = jt * 32 + jj;
    const int b  = bt * 8 + bs;
    const float* xp = x + (size_t)b * (M_GRID * J_FEAT) + (jk >> 1);
    float acc = 0.f;
    #pragma unroll 8
    for (int m = 0; m < M_GRID; ++m)
        acc += xp[(size_t)m * J_FEAT] * c_lds[m * 32 + jj];
    out[(size_t)b * NNET + jk] = acc;
}

extern "C" void kernel_launch(void* const* d_in, const int* in_sizes, int n_in,
                              void* d_out, int out_size, void* d_ws, size_t ws_size,
                              hipStream_t stream)
{
    const float* x     = (const float*)d_in[0];
    const float* t     = (const float*)d_in[1];
    const float* W_in  = (const float*)d_in[2];
    const float* b_in  = (const float*)d_in[3];
    const float* W_h   = (const float*)d_in[4];
    const float* b_h   = (const float*)d_in[5];
    const float* W_out = (const float*)d_in[6];
    const float* b_out = (const float*)d_in[7];
    const float* ln_a  = (const float*)d_in[8];
    const float* ln_b  = (const float*)d_in[9];
    float* basesT = (float*)d_ws;   // 128*160*4 = 80 KiB

    basis_kernel<<<dim3(NNET), dim3(512), 112640, stream>>>(
        t, W_in, b_in, W_h, b_h, W_out, b_out, ln_a, ln_b, basesT);
    score_kernel<<<dim3(5, 256), dim3(256), 0, stream>>>(
        x, t, basesT, (float*)d_out);
}

// Round 10
// 77.813 us; speedup vs baseline: 1.8812x; 1.6363x over previous
//
#include <hip/hip_runtime.h>
#include <math.h>

#define M_GRID 128
#define J_FEAT 80
#define NNET   160   // NBASE*J_FEAT
#define HDIM   256

typedef __attribute__((ext_vector_type(8))) short v8s;   // 8 bf16
typedef __attribute__((ext_vector_type(4))) float f4;    // MFMA accum / float4

__device__ __forceinline__ unsigned short f2bf(float f) {
    unsigned u = __float_as_uint(f);
    u += 0x7fffu + ((u >> 16) & 1u);   // round-to-nearest-even
    return (unsigned short)(u >> 16);
}

__device__ __forceinline__ float selu_f(float x) {
    const float SC = 1.0507009873554805f;
    const float AL = 1.6732632423543772f;
    return x > 0.f ? SC * x : SC * AL * (__expf(x) - 1.f);
}

// One workgroup per network n. 512 threads = 8 waves, wave w owns rows
// 16w..16w+15.  Design rule from rounds 1-9: the ONLY long-lived register
// state is acc[16] (64 regs). Everything else lives in LDS:
//   act  [wave][16 rows][256 k] bf16 (64 KB, wave-private, XOR-swizzled):
//        A-fragments are transient ds_read_b128 per stage; epilogue writes
//        act directly (C->A transpose), no reg afrag, no scr readback.
//   W    global_load_lds dwordx4 (zero regs) -> fp32 bufs 2x32KB (2 stages
//        = 64KB in flight), cooperative convert -> ONE 16KB swizzled bf16
//        tile (single buffer is safe: tile reads of stage q complete before
//        the pre-convert barrier of stage q+1).
//   params (14 KB) staged once.
// Sync per stage: counted vmcnt(4) + barrier (DMA landed; exact because no
// spill VMEM exists; ordered retirement makes epilogue param loads safe) ->
// convert -> lgkm(0) + barrier -> issue(q+2) -> A/B ds_reads + 16 MFMA.
// The pipeline runs CONTINUOUSLY across layers (epilogue overlaps the next
// layer's stage-0/1 DMAs).  LDS: buf0 @0, buf1 @32K, tile @64K, act @80K,
// params @144K; total 158 KB.
__attribute__((amdgpu_flat_work_group_size(512, 512)))
__global__ void basis_kernel(const float* __restrict__ t,
                             const float* __restrict__ W_in,
                             const float* __restrict__ b_in,
                             const float* __restrict__ W_h,
                             const float* __restrict__ b_h,
                             const float* __restrict__ W_out,
                             const float* __restrict__ b_out,
                             const float* __restrict__ ln_a,
                             const float* __restrict__ ln_b,
                             float* __restrict__ basesT)   // [M][NNET]
{
    extern __shared__ __align__(16) unsigned char lds[];   // 161792 B
    const int n    = blockIdx.x;
    const int tid  = threadIdx.x;
    const int l    = tid & 63;
    const int wv   = tid >> 6;      // wave 0..7
    const int lr   = l & 15;
    const int g    = l >> 4;        // k-group
    const int jcol = tid & 255;     // convert column
    const int o8   = tid >> 8;      // convert k-half (0/1)

    unsigned char* const actw = lds + 81920 + (size_t)wv * 8192;
    float* const P = (float*)(lds + 147456);
    // P groups (256 floats each): 0=wo, 1-3=ln_a L1..3, 4-6=ln_b L1..3,
    // 7-9=b_h L0..2, 10=wi, 11=bi, 12=ln_a L0, 13=ln_b L0.

    // ---------------- params -> LDS (only VMEM before the DMAs) ----------------
    {
        const size_t nb = (size_t)n * HDIM;
        #pragma unroll
        for (int i = 0; i < 7; ++i) {
            const int idx = tid + (i << 9), grp = idx >> 8, off = idx & 255;
            float v;
            if (grp == 0)       v = W_out[nb + off];
            else if (grp < 4)   v = ln_a[((size_t)grp * NNET + n) * HDIM + off];
            else if (grp < 7)   v = ln_b[((size_t)(grp - 3) * NNET + n) * HDIM + off];
            else if (grp < 10)  v = b_h[((size_t)(grp - 7) * NNET + n) * HDIM + off];
            else if (grp == 10) v = W_in[nb + off];
            else if (grp == 11) v = b_in[nb + off];
            else if (grp == 12) v = ln_a[nb + off];
            else                v = ln_b[nb + off];
            P[idx] = v;
        }
    }
    __syncthreads();   // params visible; drains only param loads (no DMAs yet)

    // ---------------- staging helpers ----------------
    auto issue = [&](int q) {   // stage q: 32 k-rows x 256 j fp32 -> buf(q&1)
        unsigned char* dst = lds + ((size_t)(q & 1) << 15);
        const float* Wq = W_h + ((size_t)((q >> 3) * NNET + n) << 16)
                        + (size_t)(q & 7) * 32 * HDIM + (l << 2);
        #pragma unroll
        for (int i = 0; i < 4; ++i) {
            const int r = wv * 4 + i;
            __builtin_amdgcn_global_load_lds(
                (const __attribute__((address_space(1))) void*)(Wq + (size_t)r * HDIM),
                (__attribute__((address_space(3))) void*)(dst + (size_t)r * 1024),
                16, 0, 0);
        }
    };
    auto convert = [&](int q) { // fp32 buf(q&1) -> bf16 tile [2 kh][256 j][16 k]
        const unsigned char* src = lds + ((size_t)(q & 1) << 15);
        #pragma unroll
        for (int o = 0; o < 2; ++o) {
            v8s pk;
            #pragma unroll
            for (int i2 = 0; i2 < 8; ++i2) {
                const int k = o8 * 16 + o * 8 + i2;
                pk[i2] = (short)f2bf(*(const float*)(src + (size_t)k * 1024 + (jcol << 2)));
            }
            int byte = 65536 + (o8 << 13) + jcol * 32 + (o << 4);
            byte ^= ((jcol >> 2) & 7) << 4;
            *(v8s*)(lds + byte) = pk;
        }
    };

    issue(0);
    issue(1);

    // ---------------- input layer (LDS params; output straight to act) --------
    const float tval = t[wv * 16 + lr];
    {
        const float* wi = P + 2560; const float* bi = P + 2816;
        const float* la = P + 3072; const float* lb = P + 3328;
        float s_ = 0.f, q_ = 0.f;
        #pragma unroll
        for (int kt = 0; kt < 8; ++kt) {
            const int h0 = kt * 32 + g * 8;
            const f4 w0 = *(const f4*)(wi + h0), w1 = *(const f4*)(wi + h0 + 4);
            const f4 b0 = *(const f4*)(bi + h0), b1 = *(const f4*)(bi + h0 + 4);
            #pragma unroll
            for (int i = 0; i < 4; ++i) {
                float v0 = __builtin_fmaf(tval, w0[i], b0[i]);
                float v1 = __builtin_fmaf(tval, w1[i], b1[i]);
                s_ += v0 + v1; q_ += v0 * v0 + v1 * v1;
            }
        }
        s_ += __shfl_xor(s_, 16); q_ += __shfl_xor(q_, 16);
        s_ += __shfl_xor(s_, 32); q_ += __shfl_xor(q_, 32);
        const float mean = s_ * (1.f / 256.f);
        const float var  = (q_ - s_ * s_ * (1.f / 256.f)) * (1.f / 255.f); // unbiased
        const float inv  = 1.f / (sqrtf(var) + 1e-6f);                     // eps on std
        asm volatile("" ::: "memory");   // forbid CSE of pass-1 reads
        #pragma unroll
        for (int kt = 0; kt < 8; ++kt) {
            const int h0 = kt * 32 + g * 8;
            const f4 w0 = *(const f4*)(wi + h0), w1 = *(const f4*)(wi + h0 + 4);
            const f4 b0 = *(const f4*)(bi + h0), b1 = *(const f4*)(bi + h0 + 4);
            const f4 a0 = *(const f4*)(la + h0), a1 = *(const f4*)(la + h0 + 4);
            const f4 e0 = *(const f4*)(lb + h0), e1 = *(const f4*)(lb + h0 + 4);
            v8s a;
            #pragma unroll
            for (int i = 0; i < 4; ++i) {
                float v0 = __builtin_fmaf(tval, w0[i], b0[i]);
                float v1 = __builtin_fmaf(tval, w1[i], b1[i]);
                a[i]     = (short)f2bf(selu_f(v0 + (v0 - mean) * inv * a0[i] + e0[i]));
                a[i + 4] = (short)f2bf(selu_f(v1 + (v1 - mean) * inv * a1[i] + e1[i]));
            }
            *(v8s*)(actw + ((lr * 512 + h0 * 2) ^ (lr << 5))) = a;
        }
        asm volatile("s_waitcnt lgkmcnt(0)" ::: "memory");
        __builtin_amdgcn_sched_barrier(0);
    }

    f4 acc[16];

    #pragma unroll 1
    for (int L = 0; L < 3; ++L) {
        const f4 zero = {0.f, 0.f, 0.f, 0.f};
        #pragma unroll
        for (int ct = 0; ct < 16; ++ct) acc[ct] = zero;

        #pragma unroll
        for (int s = 0; s < 8; ++s) {
            // stage q = L*8+s: my 4 DMAs for q done (4 for q+1 may stay in flight)
            if (L == 2 && s == 7) asm volatile("s_waitcnt vmcnt(0)" ::: "memory");
            else                  asm volatile("s_waitcnt vmcnt(4)" ::: "memory");
            __builtin_amdgcn_sched_barrier(0);
            __builtin_amdgcn_s_barrier();           // all waves' stage-q DMAs landed
            __builtin_amdgcn_sched_barrier(0);
            convert(L * 8 + s);
            asm volatile("s_waitcnt lgkmcnt(0)" ::: "memory");
            __builtin_amdgcn_sched_barrier(0);
            __builtin_amdgcn_s_barrier();           // tile visible; fp32 buf free
            __builtin_amdgcn_sched_barrier(0);
            if (L * 8 + s + 2 < 24) issue(L * 8 + s + 2);   // refill buf(q&1)
            // MFMA stage: A-frag from act (transient), 16 B-frags from tile
            const v8s af = *(const v8s*)(actw + ((lr * 512 + (s * 32 + g * 8) * 2) ^ (lr << 5)));
            #pragma unroll
            for (int ct = 0; ct < 16; ++ct) {
                const int jb = ct * 16 + lr;
                int byte = 65536 + ((g >> 1) << 13) + jb * 32 + ((g & 1) << 4);
                byte ^= ((jb >> 2) & 7) << 4;
                const v8s bf = *(const v8s*)(lds + byte);
                acc[ct] = __builtin_amdgcn_mfma_f32_16x16x32_bf16(af, bf, acc[ct], 0, 0, 0);
            }
        }

        // ---------------- epilogue (params from LDS) ----------------
        const float* bh = P + (7 + L) * 256;
        const float* la = P + (1 + L) * 256;
        const float* lb = P + (4 + L) * 256;

        float sums[4] = {0,0,0,0}, sqs[4] = {0,0,0,0};
        #pragma unroll
        for (int ct = 0; ct < 16; ++ct) {
            const float bias = bh[ct * 16 + lr];
            #pragma unroll
            for (int r = 0; r < 4; ++r) {
                float v = acc[ct][r] + bias;
                acc[ct][r] = v;
                sums[r] += v; sqs[r] += v * v;
            }
        }
        #pragma unroll
        for (int r = 0; r < 4; ++r)
            #pragma unroll
            for (int m = 1; m <= 8; m <<= 1) {
                sums[r] += __shfl_xor(sums[r], m);
                sqs[r]  += __shfl_xor(sqs[r],  m);
            }
        float mean[4], inv[4];
        #pragma unroll
        for (int r = 0; r < 4; ++r) {
            mean[r] = sums[r] * (1.f / 256.f);
            float var = (sqs[r] - sums[r] * sums[r] * (1.f / 256.f)) * (1.f / 255.f);
            inv[r] = 1.f / (sqrtf(var) + 1e-6f);
        }

        if (L < 2) {
            // C layout (row=4g+r, col=ct*16+lr) -> act (wave-private transpose)
            #pragma unroll
            for (int ct = 0; ct < 16; ++ct) {
                const float a_ = la[ct * 16 + lr], b_ = lb[ct * 16 + lr];
                #pragma unroll
                for (int r = 0; r < 4; ++r) {
                    float v  = acc[ct][r];
                    float sv = selu_f(v + (v - mean[r]) * inv[r] * a_ + b_);
                    const int row = 4 * g + r;
                    *(unsigned short*)(actw + ((row * 512 + (ct * 16 + lr) * 2) ^ (row << 5)))
                        = f2bf(sv);
                }
            }
            asm volatile("s_waitcnt lgkmcnt(0)" ::: "memory");  // act writes done
            __builtin_amdgcn_sched_barrier(0);
        } else {
            // fused output layer
            const float bo = b_out[n];
            float ps[4] = {0,0,0,0};
            #pragma unroll
            for (int ct = 0; ct < 16; ++ct) {
                const float a_ = la[ct * 16 + lr], b_ = lb[ct * 16 + lr];
                const float w_ = P[ct * 16 + lr];   // wo
                #pragma unroll
                for (int r = 0; r < 4; ++r) {
                    float v  = acc[ct][r];
                    float sv = selu_f(v + (v - mean[r]) * inv[r] * a_ + b_);
                    ps[r] += sv * w_;
                }
            }
            #pragma unroll
            for (int r = 0; r < 4; ++r)
                #pragma unroll
                for (int m = 1; m <= 8; m <<= 1)
                    ps[r] += __shfl_xor(ps[r], m);
            #pragma unroll
            for (int r = 0; r < 4; ++r)
                if (lr == r)
                    basesT[(size_t)(wv * 16 + 4 * g + r) * NNET + n] = ps[r] + bo;
        }
    }
}

// score[b, jk] = sum_m x[b,m,jk>>1] * basesT[m][jk] * w[m]
__launch_bounds__(256)
__global__ void score_kernel(const float* __restrict__ x,
                             const float* __restrict__ t,
                             const float* __restrict__ basesT,
                             float* __restrict__ out)
{
    __shared__ float c_lds[M_GRID * 32];
    const int jt  = blockIdx.x;   // 0..4
    const int bt  = blockIdx.y;   // 0..255
    const int tid = threadIdx.x;

    for (int i = tid; i < M_GRID * 32; i += 256) {
        const int m  = i >> 5;
        const int jl = i & 31;
        const float tp = t[m == M_GRID - 1 ? M_GRID - 1 : m + 1];
        const float tm = t[m == 0 ? 0 : m - 1];
        c_lds[i] = basesT[(size_t)m * NNET + jt * 32 + jl] * 0.5f * (tp - tm);
    }
    __syncthreads();

    const int jj = tid & 31;
    const int bs = tid >> 5;
    const int jk = jt * 32 + jj;
    const int b  = bt * 8 + bs;
    const float* xp = x + (size_t)b * (M_GRID * J_FEAT) + (jk >> 1);
    float acc = 0.f;
    #pragma unroll 8
    for (int m = 0; m < M_GRID; ++m)
        acc += xp[(size_t)m * J_FEAT] * c_lds[m * 32 + jj];
    out[(size_t)b * NNET + jk] = acc;
}

extern "C" void kernel_launch(void* const* d_in, const int* in_sizes, int n_in,
                              void* d_out, int out_size, void* d_ws, size_t ws_size,
                              hipStream_t stream)
{
    const float* x     = (const float*)d_in[0];
    const float* t     = (const float*)d_in[1];
    const float* W_in  = (const float*)d_in[2];
    const float* b_in  = (const float*)d_in[3];
    const float* W_h   = (const float*)d_in[4];
    const float* b_h   = (const float*)d_in[5];
    const float* W_out = (const float*)d_in[6];
    const float* b_out = (const float*)d_in[7];
    const float* ln_a  = (const float*)d_in[8];
    const float* ln_b  = (const float*)d_in[9];
    float* basesT = (float*)d_ws;   // 128*160*4 = 80 KiB

    basis_kernel<<<dim3(NNET), dim3(512), 161792, stream>>>(
        t, W_in, b_in, W_h, b_h, W_out, b_out, ln_a, ln_b, basesT);
    score_kernel<<<dim3(5, 256), dim3(256), 0, stream>>>(
        x, t, basesT, (float*)d_out);
}